// Round 2
// baseline (31557.614 us; speedup 1.0000x reference)
//
#include <hip/hip_runtime.h>

#define B_ 32
#define S_ 512
#define H_ 1024
#define L_ 3
#define BH (B_*H_)   // 32768
#define NBLK 192

typedef __attribute__((ext_vector_type(8))) short short8;
typedef __attribute__((ext_vector_type(4))) float f4;

__device__ __forceinline__ unsigned short f2bf(float f){
  unsigned int u = __float_as_uint(f);
  u += 0x7fffu + ((u >> 16) & 1u);   // RNE
  return (unsigned short)(u >> 16);
}
__device__ __forceinline__ float sigmoidf_(float x){
  return 1.0f / (1.0f + __expf(-x));
}

// ---------------- prep: pack weights in MFMA-fragment order -----------------
// WAp layout: [a_tile 0..383][kb 0..63][lane 0..63][j 0..7] (short)
//   a_tile = g*128 + jt ; col n(2048) = jt*16 + (lane&15); k = kb*32 + (lane>>4)*8 + j
//   n<1024: z cols (Wx/Wz), n>=1024: r cols (Wr/Wh); k<1024: input W, k>=1024: state W
__global__ void prep_WA_packed(const float* __restrict__ Wx, const float* __restrict__ Wz,
                               const float* __restrict__ Wr, const float* __restrict__ Wh,
                               unsigned short* __restrict__ WAp){
  int idx = blockIdx.x * blockDim.x + threadIdx.x;  // 384*64*64 exact
  int lane = idx & 63;
  int kb = (idx >> 6) & 63;
  int tile = idx >> 12;            // 0..383
  int g = tile >> 7, jt = tile & 127;
  int quad = lane >> 4, l15 = lane & 15;
  int n = jt * 16 + l15;           // 0..2047
  int k0 = kb * 32 + quad * 8;     // all 8 j in same 1024-half
  int col = n & 1023;
  const float* W = (k0 < 1024) ? ((n < 1024) ? Wx : Wr) : ((n < 1024) ? Wz : Wh);
  const float* src = W + ((size_t)g * 1024 + (k0 & 1023)) * 1024 + col;
  short8 v;
  #pragma unroll
  for (int j = 0; j < 8; ++j) v[j] = (short)f2bf(src[(size_t)j * 1024]);
  *(short8*)(WAp + (size_t)idx * 8) = v;
}

// WBp layout: [b_tile 0..191][kb 0..63][lane][8]; b_tile = g*64 + jt, n = jt*16+l15
__global__ void prep_WB_packed(const float* __restrict__ Wg, const float* __restrict__ Whg,
                               unsigned short* __restrict__ WBp){
  int idx = blockIdx.x * blockDim.x + threadIdx.x;  // 192*64*64 exact
  int lane = idx & 63;
  int kb = (idx >> 6) & 63;
  int tile = idx >> 12;            // 0..191
  int g = tile >> 6, jt = tile & 63;
  int quad = lane >> 4, l15 = lane & 15;
  int n = jt * 16 + l15;           // 0..1023
  int k0 = kb * 32 + quad * 8;
  const float* W = (k0 < 1024) ? Wg : Whg;
  const float* src = W + ((size_t)g * 1024 + (k0 & 1023)) * 1024 + n;
  short8 v;
  #pragma unroll
  for (int j = 0; j < 8; ++j) v[j] = (short)f2bf(src[(size_t)j * 1024]);
  *(short8*)(WBp + (size_t)idx * 8) = v;
}

// WoutP: [tile 0..63][kb 0..31][lane][8]; n = tile*16+l15, k = kb*32+quad*8+j
__global__ void prep_Wout_packed(const float* __restrict__ Wout,
                                 unsigned short* __restrict__ WoutP){
  int idx = blockIdx.x * blockDim.x + threadIdx.x;  // 64*32*64 exact
  int lane = idx & 63;
  int kb = (idx >> 6) & 31;
  int tile = idx >> 11;            // 0..63
  int quad = lane >> 4, l15 = lane & 15;
  int n = tile * 16 + l15;
  int k0 = kb * 32 + quad * 8;
  const float* src = Wout + (size_t)k0 * 1024 + n;
  short8 v;
  #pragma unroll
  for (int j = 0; j < 8; ++j) v[j] = (short)f2bf(src[(size_t)j * 1024]);
  *(short8*)(WoutP + (size_t)idx * 8) = v;
}

// Xb[t][b][i] = bf16(x[b][t][i])
__global__ void prep_X_kernel(const float* __restrict__ x, unsigned short* __restrict__ Xb){
  size_t idx = (size_t)blockIdx.x * blockDim.x + threadIdx.x;  // 512*32*1024 exact
  int i = (int)(idx & 1023);
  int b = (int)((idx >> 10) & 31);
  int t = (int)(idx >> 15);
  Xb[idx] = f2bf(x[((size_t)b * S_ + t) * 1024 + i]);
}

__global__ void prep_H0_kernel(const float* __restrict__ h0,
                               unsigned short* __restrict__ HTb, float* __restrict__ HTf){
  int idx = blockIdx.x * blockDim.x + threadIdx.x;  // 3*32*1024 exact
  int h = idx & 1023;
  int b = (idx >> 10) & 31;
  int v = idx >> 15;
  float val = h0[((size_t)b * L_ + v) * 1024 + h];
  HTb[idx] = f2bf(val);
  HTf[idx] = val;
}

// ---------------- two-level grid barrier ------------------------------------
// bar layout (uints): sub[p][x] at [p*256 + x*32], top[p] at [512+p*32], gen at [576]
__device__ __forceinline__ void gridbar(unsigned* bar, unsigned idx){
  __syncthreads();
  if (threadIdx.x == 0){
    unsigned p = idx & 1u;
    unsigned* sub = bar + p * 256 + (blockIdx.x & 7) * 32;
    unsigned* top = bar + 512 + p * 32;
    unsigned* gen = bar + 576;
    __threadfence();
    unsigned g = __hip_atomic_load(gen, __ATOMIC_RELAXED, __HIP_MEMORY_SCOPE_AGENT);
    bool done = false;
    if (atomicAdd(sub, 1u) == (NBLK / 8) - 1u){
      __hip_atomic_store(sub, 0u, __ATOMIC_RELAXED, __HIP_MEMORY_SCOPE_AGENT);
      if (atomicAdd(top, 1u) == 8u - 1u){
        __hip_atomic_store(top, 0u, __ATOMIC_RELAXED, __HIP_MEMORY_SCOPE_AGENT);
        __hip_atomic_fetch_add(gen, 1u, __ATOMIC_RELEASE, __HIP_MEMORY_SCOPE_AGENT);
        done = true;
      }
    }
    if (!done){
      while (__hip_atomic_load(gen, __ATOMIC_ACQUIRE, __HIP_MEMORY_SCOPE_AGENT) == g)
        __builtin_amdgcn_s_sleep(2);
    }
    __threadfence();
  }
  __syncthreads();
}

// ---------------- persistent recurrence kernel ------------------------------
// 192 blocks x 256 threads. Block's layer g = blk>>6 (uniform, both phases).
// Even slot (A): wave = (tile_local<<1)|mh ; a_tile = blk*2 + tile_local.
// Odd slot  (B): b_tile = blk ; wave = (mh<<1)|kh ; K split across kh, LDS reduce.
__global__ __launch_bounds__(256) void gru_persist(
    const unsigned short* __restrict__ WAp, const unsigned short* __restrict__ WBp,
    const unsigned short* __restrict__ Xb,
    unsigned short* __restrict__ h0b, unsigned short* __restrict__ h1b,
    unsigned short* __restrict__ HTb, float* __restrict__ HTf,
    float* __restrict__ zbuf, unsigned short* __restrict__ rsb,
    const float* __restrict__ bz, const float* __restrict__ br,
    const float* __restrict__ bg, unsigned* bar)
{
  __shared__ f4 red[2][64];
  const int blk = blockIdx.x;
  const int wave = threadIdx.x >> 6;
  const int lane = threadIdx.x & 63;
  const int quad = lane >> 4, l15 = lane & 15;
  const int g = blk >> 6;              // layer (uniform per block)
  unsigned bidx = 0;

  for (int s = -4; s <= 2 * S_ - 1; ++s){
    int u = (((s & 1) ? (s - 1) : s)) / 2;   // exact division (even numerator)
    int t = u + 2 - g;
    bool active = (t >= 0) && (t < S_);
    int tm = t & 3;
    int v = u + 2;                           // state index read this slot

    if ((s & 1) == 0){
      if (active){
        const unsigned short* inp = (g == 0) ? Xb + (size_t)t * BH
                                  : (g == 1) ? h0b + (size_t)tm * BH
                                             : h1b + (size_t)tm * BH;
        const unsigned short* sb = HTb + (size_t)v * BH;
        int tl = wave >> 1, mh = wave & 1;
        int a_tile = blk * 2 + tl;
        int jt = a_tile & 127;
        const unsigned short* arow = inp + (mh * 16 + l15) * H_;
        const unsigned short* srow = sb  + (mh * 16 + l15) * H_;
        const short8* bp = (const short8*)WAp + (size_t)a_tile * 64 * 64 + lane;
        f4 acc = {0.f, 0.f, 0.f, 0.f};
        #pragma unroll 8
        for (int kb = 0; kb < 64; ++kb){
          int k0 = kb * 32 + quad * 8;
          short8 a = (kb < 32) ? *(const short8*)(arow + k0)
                               : *(const short8*)(srow + k0 - 1024);
          short8 bv = bp[(size_t)kb * 64];
          acc = __builtin_amdgcn_mfma_f32_16x16x32_bf16(a, bv, acc, 0, 0, 0);
        }
        int n2 = jt * 16 + l15;
        const float* sf = HTf + (size_t)(v & 7) * BH;
        if (n2 < 1024){
          float bias = bz[g * H_ + n2];
          float* zb = zbuf + (size_t)(g * 4 + tm) * BH;
          #pragma unroll
          for (int r = 0; r < 4; ++r){
            int b = mh * 16 + quad * 4 + r;
            zb[b * H_ + n2] = sigmoidf_(acc[r] + bias);
          }
        } else {
          int n = n2 - 1024;
          float bias = br[g * H_ + n];
          unsigned short* rs = rsb + (size_t)(g * 4 + tm) * BH;
          #pragma unroll
          for (int r = 0; r < 4; ++r){
            int b = mh * 16 + quad * 4 + r;
            rs[b * H_ + n] = f2bf(sigmoidf_(acc[r] + bias) * sf[b * H_ + n]);
          }
        }
      }
    } else {
      if (active){
        const unsigned short* inp = (g == 0) ? Xb + (size_t)t * BH
                                  : (g == 1) ? h0b + (size_t)tm * BH
                                             : h1b + (size_t)tm * BH;
        const unsigned short* rs = rsb + (size_t)(g * 4 + tm) * BH;
        int mh = wave >> 1, kh = wave & 1;
        int jt = blk & 63;
        const unsigned short* arow = inp + (mh * 16 + l15) * H_;
        const unsigned short* rrow = rs  + (mh * 16 + l15) * H_;
        const short8* bp = (const short8*)WBp + (size_t)blk * 64 * 64 + lane;
        f4 acc = {0.f, 0.f, 0.f, 0.f};
        #pragma unroll 8
        for (int kk = 0; kk < 32; ++kk){
          int kb = kh * 32 + kk;
          int k0 = kb * 32 + quad * 8;
          short8 a = (kh == 0) ? *(const short8*)(arow + k0)
                               : *(const short8*)(rrow + k0 - 1024);
          short8 bv = bp[(size_t)kb * 64];
          acc = __builtin_amdgcn_mfma_f32_16x16x32_bf16(a, bv, acc, 0, 0, 0);
        }
        if (kh) red[mh][lane] = acc;
        __syncthreads();
        if (!kh){
          f4 o = red[mh][lane];
          acc = acc + o;
          int n = jt * 16 + l15;
          const float* sf = HTf + (size_t)(v & 7) * BH;
          const float* zb = zbuf + (size_t)(g * 4 + tm) * BH;
          float bias = bg[g * H_ + n];
          #pragma unroll
          for (int r = 0; r < 4; ++r){
            int b = mh * 16 + quad * 4 + r;
            float gg = tanhf(acc[r] + bias);
            float z = zb[b * H_ + n];
            float h = z * sf[b * H_ + n] + (1.f - z) * gg;
            if (g == 2){
              HTf[(size_t)((t + 3) & 7) * BH + b * H_ + n] = h;
              HTb[(size_t)(t + 3) * BH + b * H_ + n] = f2bf(h);
            } else if (g == 0){
              h0b[(size_t)tm * BH + b * H_ + n] = f2bf(h);
            } else {
              h1b[(size_t)tm * BH + b * H_ + n] = f2bf(h);
            }
          }
        }
      }
    }
    gridbar(bar, bidx++);
  }
}

// ---------------- epilogue: Y = HT @ Wout + bout ----------------------------
__global__ __launch_bounds__(256) void out_proj_kernel(
    const unsigned short* __restrict__ HTb, const unsigned short* __restrict__ WoutP,
    const float* __restrict__ bout, float* __restrict__ Y){
  int tstep = blockIdx.x >> 2;
  int nblk  = blockIdx.x & 3;
  int wave = threadIdx.x >> 6, lane = threadIdx.x & 63;
  int quad = lane >> 4, l15 = lane & 15;
  const unsigned short* A = HTb + (size_t)(tstep + 3) * BH;
  f4 acc[2][4] = {};
  for (int kk = 0; kk < 32; ++kk){
    int k0 = kk * 32 + quad * 8;
    short8 a0 = *(const short8*)(A + l15 * H_ + k0);
    short8 a1 = *(const short8*)(A + (l15 + 16) * H_ + k0);
    #pragma unroll
    for (int nt = 0; nt < 4; ++nt){
      int tile = nblk * 16 + wave * 4 + nt;
      short8 bv = ((const short8*)WoutP)[((size_t)tile * 32 + kk) * 64 + lane];
      acc[0][nt] = __builtin_amdgcn_mfma_f32_16x16x32_bf16(a0, bv, acc[0][nt], 0, 0, 0);
      acc[1][nt] = __builtin_amdgcn_mfma_f32_16x16x32_bf16(a1, bv, acc[1][nt], 0, 0, 0);
    }
  }
  #pragma unroll
  for (int mt = 0; mt < 2; ++mt)
    #pragma unroll
    for (int nt = 0; nt < 4; ++nt)
      #pragma unroll
      for (int r = 0; r < 4; ++r){
        int b = mt * 16 + quad * 4 + r;
        int n = nblk * 256 + wave * 64 + nt * 16 + l15;
        Y[(size_t)b * (S_ * 1024) + (size_t)tstep * 1024 + n] = acc[mt][nt][r] + bout[n];
      }
}

__global__ void copy_hidden_kernel(const float* __restrict__ HTf, float* __restrict__ out2){
  int idx = blockIdx.x * blockDim.x + threadIdx.x;  // 3*32*1024 exact
  int h = idx & 1023;
  int b = (idx >> 10) & 31;
  int v = idx >> 15;
  out2[((size_t)b * L_ + v) * 1024 + h] = HTf[(size_t)((S_ + v) & 7) * BH + b * H_ + h];
}

// ---------------------------------------------------------------------------
extern "C" void kernel_launch(void* const* d_in, const int* in_sizes, int n_in,
                              void* d_out, int out_size, void* d_ws, size_t ws_size,
                              hipStream_t stream){
  (void)in_sizes; (void)n_in; (void)out_size;
  const float* x    = (const float*)d_in[0];
  const float* h0   = (const float*)d_in[1];
  const float* Wx   = (const float*)d_in[2];
  const float* Wz   = (const float*)d_in[3];
  const float* bz   = (const float*)d_in[4];
  const float* Wr   = (const float*)d_in[5];
  const float* Wh   = (const float*)d_in[6];
  const float* br   = (const float*)d_in[7];
  const float* Wg   = (const float*)d_in[8];
  const float* Whg  = (const float*)d_in[9];
  const float* bg   = (const float*)d_in[10];
  const float* Wout = (const float*)d_in[11];
  const float* bout = (const float*)d_in[12];
  float* out = (float*)d_out;

  char* p = (char*)d_ws;
  unsigned short* WAp   = (unsigned short*)p; p += (size_t)384 * 64 * 64 * 8 * 2;
  unsigned short* WBp   = (unsigned short*)p; p += (size_t)192 * 64 * 64 * 8 * 2;
  unsigned short* WoutP = (unsigned short*)p; p += (size_t)64 * 32 * 64 * 8 * 2;
  unsigned short* Xb    = (unsigned short*)p; p += (size_t)S_ * BH * 2;
  unsigned short* HTb   = (unsigned short*)p; p += (size_t)(S_ + 3) * BH * 2;
  float*          HTf   = (float*)p;          p += (size_t)8 * BH * 4;
  unsigned short* h0b   = (unsigned short*)p; p += (size_t)4 * BH * 2;
  unsigned short* h1b   = (unsigned short*)p; p += (size_t)4 * BH * 2;
  float*          zbuf  = (float*)p;          p += (size_t)3 * 4 * BH * 4;
  unsigned short* rsb   = (unsigned short*)p; p += (size_t)3 * 4 * BH * 2;
  unsigned*       bar   = (unsigned*)p;       p += 4096;
  if ((size_t)(p - (char*)d_ws) > ws_size) return;

  hipMemsetAsync(bar, 0, 4096, stream);
  prep_WA_packed  <<<6144, 256, 0, stream>>>(Wx, Wz, Wr, Wh, WAp);
  prep_WB_packed  <<<3072, 256, 0, stream>>>(Wg, Whg, WBp);
  prep_Wout_packed<<< 512, 256, 0, stream>>>(Wout, WoutP);
  prep_X_kernel   <<<65536, 256, 0, stream>>>(x, Xb);
  prep_H0_kernel  <<<  384, 256, 0, stream>>>(h0, HTb, HTf);

  gru_persist<<<NBLK, 256, 0, stream>>>(WAp, WBp, Xb, h0b, h1b, HTb, HTf,
                                        zbuf, rsb, bz, br, bg, bar);

  out_proj_kernel   <<<2048, 256, 0, stream>>>(HTb, WoutP, bout, out);
  copy_hidden_kernel<<< 384, 256, 0, stream>>>(HTf, out + (size_t)B_ * S_ * 1024);
}